// Round 7
// baseline (655.915 us; speedup 1.0000x reference)
//
#include <hip/hip_runtime.h>
#include <hip/hip_bf16.h>
#include <stdint.h>

#define N_NODES 50000
#define N_EDGES 800000
#define IN_DIM 64
#define HID 128
#define OUT_DIM 64
#define T_HIST 8

typedef __attribute__((ext_vector_type(8))) short short8;
typedef __attribute__((ext_vector_type(4))) float f32x4;

__device__ __forceinline__ unsigned short f2bf(float x) {
  unsigned int u = __builtin_bit_cast(unsigned int, x);
  unsigned int r = (u + 0x7FFFu + ((u >> 16) & 1u)) >> 16;
  return (unsigned short)r;
}
__device__ __forceinline__ short8 cvt8(float4 a, float4 b) {
  unsigned int w0, w1, w2, w3;
  asm("v_cvt_pk_bf16_f32 %0, %1, %2" : "=v"(w0) : "v"(a.x), "v"(a.y));
  asm("v_cvt_pk_bf16_f32 %0, %1, %2" : "=v"(w1) : "v"(a.z), "v"(a.w));
  asm("v_cvt_pk_bf16_f32 %0, %1, %2" : "=v"(w2) : "v"(b.x), "v"(b.y));
  asm("v_cvt_pk_bf16_f32 %0, %1, %2" : "=v"(w3) : "v"(b.z), "v"(b.w));
  struct { unsigned int a, b, c, d; } s{w0, w1, w2, w3};
  return __builtin_bit_cast(short8, s);
}
// sigmoid/tanh via exp2+rcp; safe at +-inf
__device__ __forceinline__ float sigm(float x) {
  float e = __builtin_amdgcn_exp2f(-1.4426950408889634f * x);
  return __builtin_amdgcn_rcpf(1.f + e);
}
__device__ __forceinline__ float tanh_f(float x) {
  float e = __builtin_amdgcn_exp2f(2.8853900817779268f * x);
  return 1.f - 2.f * __builtin_amdgcn_rcpf(e + 1.f);
}

// ---------------- prepack: bf16 frag weights + folded classifier weights + cnt zero ----------------
__global__ void prepack_kernel(const float* __restrict__ w_ih, const float* __restrict__ w_hh,
                               const float* __restrict__ W_cls,
                               const float* __restrict__ W_self, const float* __restrict__ W_neigh,
                               const float* __restrict__ b_sage, const float* __restrict__ b_cls,
                               unsigned short* __restrict__ Wt2, unsigned short* __restrict__ Wc2,
                               float* __restrict__ Wsc, float* __restrict__ Wnc,
                               float* __restrict__ bc1, int* __restrict__ cnt) {
  int tid = blockIdx.x * blockDim.x + threadIdx.x;
  int stride = gridDim.x * blockDim.x;
  for (int i = tid; i < N_NODES; i += stride) cnt[i] = 0;
  for (int idx = tid; idx < 256 * 512; idx += stride) {
    int i = idx & 7;
    int lane = (idx >> 3) & 63;
    int F = idx >> 9;
    int q = F >> 5, g = (F >> 3) & 3, kk = F & 7;
    int c = g * 128 + q * 16 + (lane & 15);
    int k = kk * 32 + (lane >> 4) * 8 + i;
    float v = (k < 128) ? w_ih[k * 512 + c] : w_hh[(k - 128) * 512 + c];
    Wt2[idx] = f2bf(v);
  }
  for (int idx = tid; idx < 16 * 512; idx += stride) {
    int i = idx & 7;
    int lane = (idx >> 3) & 63;
    int F = idx >> 9;
    int cb = F >> 2, kk = F & 3;
    int col = cb * 16 + (lane & 15);
    int k = kk * 32 + (lane >> 4) * 8 + i;
    Wc2[idx] = f2bf(W_cls[k * 64 + col]);
  }
  for (int idx = tid; idx < 64 * 64; idx += stride) {
    int k = idx >> 6, c = idx & 63;
    float as = 0.f, an = 0.f;
    for (int m = 0; m < 128; m++) {
      float wc = W_cls[m * 64 + c];
      as += W_self[k * 128 + m] * wc;
      an += W_neigh[k * 128 + m] * wc;
    }
    Wsc[idx] = as;
    Wnc[idx] = an;
  }
  for (int c = tid; c < 64; c += stride) {
    float acc = b_cls[c];
    for (int m = 0; m < 128; m++) acc += b_sage[m] * W_cls[m * 64 + c];
    bc1[c] = acc;
  }
}

// ---------------- CSR build ----------------
__global__ void count_kernel(const int* __restrict__ dst, int* __restrict__ cnt) {
  int e = blockIdx.x * blockDim.x + threadIdx.x;
  if (e < N_EDGES) atomicAdd(&cnt[dst[e]], 1);
}

__global__ __launch_bounds__(1024) void scan_kernel(const int* __restrict__ cnt,
                                                    int* __restrict__ rowstart,
                                                    int* __restrict__ cursor) {
  __shared__ int sh[1024];
  int tid = threadIdx.x;
  const int C = 49;
  int b0 = tid * C;
  int tsum = 0;
  for (int j = 0; j < C; j++) {
    int i = b0 + j;
    if (i < N_NODES) tsum += cnt[i];
  }
  sh[tid] = tsum;
  __syncthreads();
  int val = tsum;
  for (int off = 1; off < 1024; off <<= 1) {
    int x = (tid >= off) ? sh[tid - off] : 0;
    __syncthreads();
    val += x;
    sh[tid] = val;
    __syncthreads();
  }
  int run = val - tsum;  // exclusive prefix
  for (int j = 0; j < C; j++) {
    int i = b0 + j;
    if (i < N_NODES) { rowstart[i] = run; cursor[i] = run; run += cnt[i]; }
  }
}

__global__ void fill_kernel(const int* __restrict__ src, const int* __restrict__ dst,
                            int* __restrict__ cursor, int* __restrict__ esrc) {
  int e = blockIdx.x * blockDim.x + threadIdx.x;
  if (e < N_EDGES) {
    int d = dst[e];
    int pos = atomicAdd(&cursor[d], 1);
    esrc[pos] = src[e];
  }
}

// ---------------- out1 = nf@Wsc + mean_neigh@Wnc + bc1 (classifier pre-folded) ----------------
#define HS_TILE 32
__global__ __launch_bounds__(256) void hstruct_kernel(
    const float* __restrict__ nf, const int* __restrict__ esrc,
    const int* __restrict__ rowstart, const int* __restrict__ cnt,
    const float* __restrict__ Wsc, const float* __restrict__ Wnc, const float* __restrict__ bc1,
    float* __restrict__ out1) {
  __shared__ float s_nf[HS_TILE][IN_DIM + 1];
  __shared__ float s_hn[HS_TILE][IN_DIM + 1];
  int tid = threadIdx.x;
  int node0 = blockIdx.x * HS_TILE;
  for (int i = tid; i < HS_TILE * IN_DIM; i += 256) {
    int r = i >> 6, k = i & 63;
    int node = node0 + r;
    s_nf[r][k] = (node < N_NODES) ? nf[node * 64 + k] : 0.f;
  }
  int wv = tid >> 6, lane = tid & 63;
  for (int r = wv; r < HS_TILE; r += 4) {
    int node = node0 + r;
    float a0 = 0.f, a1 = 0.f, a2 = 0.f, a3 = 0.f;
    int n = 0;
    if (node < N_NODES) {
      n = cnt[node];
      int st = rowstart[node];
      int j = 0;
      for (; j + 4 <= n; j += 4) {
        int s0 = esrc[st + j], s1 = esrc[st + j + 1];
        int s2 = esrc[st + j + 2], s3 = esrc[st + j + 3];
        a0 += nf[s0 * 64 + lane];
        a1 += nf[s1 * 64 + lane];
        a2 += nf[s2 * 64 + lane];
        a3 += nf[s3 * 64 + lane];
      }
      for (; j < n; j++) a0 += nf[esrc[st + j] * 64 + lane];
    }
    s_hn[r][lane] = (a0 + a1 + a2 + a3) * __builtin_amdgcn_rcpf(fmaxf((float)n, 1.f));
  }
  __syncthreads();
  int r = tid & 31;
  int c0 = (tid >> 5) * 8;
  float accs[8];
  #pragma unroll
  for (int i = 0; i < 8; i++) accs[i] = 0.f;
  for (int k = 0; k < IN_DIM; k++) {
    float a = s_nf[r][k];
    float b = s_hn[r][k];
    const float4* ws = (const float4*)&Wsc[k * 64 + c0];
    const float4* wn = (const float4*)&Wnc[k * 64 + c0];
    #pragma unroll
    for (int q2 = 0; q2 < 2; q2++) {
      float4 w1 = ws[q2]; float4 w2 = wn[q2];
      accs[q2*4+0] += a * w1.x + b * w2.x;
      accs[q2*4+1] += a * w1.y + b * w2.y;
      accs[q2*4+2] += a * w1.z + b * w2.z;
      accs[q2*4+3] += a * w1.w + b * w2.w;
    }
  }
  int node = node0 + r;
  if (node < N_NODES) {
    #pragma unroll
    for (int i = 0; i < 8; i++)
      out1[(size_t)node * 64 + c0 + i] = accs[i] + bc1[c0 + i];
  }
}

// ---------------- fused LSTM + classifier: gate-split wave pairs ----------------
// 1024 thr = 16 waves. Wave (q = w>>1, h = w&1): cols jj in [16q,16q+16),
// gates {i,f} (h=0) or {g,o} (h=1). Bfr = 64 VGPR -> 4 waves/SIMD.
// h=1 publishes pre-activation g,o (bias folded) via fp32 Gbuf per 32-row half;
// h=0 owns c_st + cell updates; h=1 stages x(t+1) in the cell-phase shadow.
#define LB 64
__global__ __launch_bounds__(1024, 4) void lstm_kernel(
    const float* __restrict__ hist,          // [N][8][128] f32
    const unsigned short* __restrict__ Wt2,  // frag-ordered bf16
    const unsigned short* __restrict__ Wc2,  // frag-ordered bf16
    const float* __restrict__ b_lstm,        // [512]
    const float* __restrict__ out1,          // [N][64] fp32 (classifier partial)
    float* __restrict__ out)                 // [N][64]
{
  __shared__ alignas(16) unsigned short Abuf[2][LB * 256];  // 2 x 32KB
  __shared__ alignas(16) float Gbuf[2][32 * 128 * 2];       // 2 x 32KB [half][lr][jj][gate]

  const int tid = threadIdx.x;
  const int lane = tid & 63;
  const int w = tid >> 6;      // 0..15
  const int q = w >> 1;        // col-group 0..7
  const int h = w & 1;         // gate-team
  const int l15 = lane & 15;
  const int l4 = lane >> 4;
  const int base = blockIdx.x * LB;
  const int jj = q * 16 + l15;

  // persistent B fragments: this team's 2 gates x 8 kk = 64 VGPR
  short8 Bfr[2][8];
  #pragma unroll
  for (int gg = 0; gg < 2; gg++)
    #pragma unroll
    for (int kk = 0; kk < 8; kk++)
      Bfr[gg][kk] = *(const short8*)&Wt2[((q * 32 + (2 * h + gg) * 8 + kk) * 64 + lane) * 8];

  // team biases: h=0 -> {bi, bf}; h=1 -> {bg, bo} (folded into G write)
  const float bA = b_lstm[(2 * h + 0) * 128 + jj];
  const float bB = b_lstm[(2 * h + 1) * 128 + jj];

  float c_st[16];
  #pragma unroll
  for (int i = 0; i < 16; i++) c_st[i] = 0.f;

  // prologue: zero h-region of buf0 + stage x(0); 1024 units
  {
    int u = tid;
    int row = u >> 4, kb = u & 15;
    short8 z = {0,0,0,0,0,0,0,0};
    *(short8*)&Abuf[0][row * 256 + 128 + kb * 8] = z;
    int node = base + row;
    float4 x0 = make_float4(0.f,0.f,0.f,0.f), x1 = make_float4(0.f,0.f,0.f,0.f);
    if (node < N_NODES) {
      const float4* p = (const float4*)&hist[(size_t)node * (T_HIST * HID) + kb * 8];
      x0 = p[0]; x1 = p[1];
    }
    int sb = (kb & 8) | ((kb & 7) ^ (row & 7));
    *(short8*)&Abuf[0][row * 256 + sb * 8] = cvt8(x0, x1);
  }
  __syncthreads();

  const int su = q * 64 + lane;          // h=1 staging unit 0..511
  const int srl = su >> 4, skb = su & 15;

  #pragma unroll
  for (int t = 0; t < T_HIST; t++) {
    unsigned short* Acur = &Abuf[t & 1][0];
    unsigned short* Anxt = &Abuf[(t & 1) ^ 1][0];

    // h=1: issue x(t+1) loads for both halves early (hidden under MFMA)
    float4 xp[2][2];
    if (h == 1 && t < T_HIST - 1) {
      #pragma unroll
      for (int H = 0; H < 2; H++) {
        int row = H * 32 + srl;
        int node = base + row;
        if (node < N_NODES) {
          const float4* p = (const float4*)&hist[(size_t)node * (T_HIST * HID) + (t + 1) * HID + skb * 8];
          xp[H][0] = p[0]; xp[H][1] = p[1];
        } else {
          xp[H][0] = make_float4(0.f,0.f,0.f,0.f);
          xp[H][1] = make_float4(0.f,0.f,0.f,0.f);
        }
      }
    }

    #pragma unroll
    for (int H = 0; H < 2; H++) {
      f32x4 accH[2][2];   // held by h=0: [rbl][gate i/f]
      #pragma unroll
      for (int rbl = 0; rbl < 2; rbl++) {
        int rb = H * 2 + rbl;
        f32x4 a0 = {0.f,0.f,0.f,0.f}, a1 = {0.f,0.f,0.f,0.f};
        #pragma unroll
        for (int kk = 0; kk < 8; kk++) {
          int row = rb * 16 + l15;
          int kb = kk * 4 + l4;
          int sb = (kb & 24) | ((kb & 7) ^ (row & 7));
          short8 a = *(const short8*)&Acur[row * 256 + sb * 8];
          a0 = __builtin_amdgcn_mfma_f32_16x16x32_bf16(a, Bfr[0][kk], a0, 0, 0, 0);
          a1 = __builtin_amdgcn_mfma_f32_16x16x32_bf16(a, Bfr[1][kk], a1, 0, 0, 0);
        }
        if (h == 1) {
          // publish pre-activation g,o with bias folded
          #pragma unroll
          for (int reg = 0; reg < 4; reg++) {
            int lr = rbl * 16 + l4 * 4 + reg;
            float2 v = make_float2(a0[reg] + bA, a1[reg] + bB);
            *(float2*)&Gbuf[H][(lr * 128 + jj) * 2] = v;
          }
        } else {
          accH[rbl][0] = a0; accH[rbl][1] = a1;
        }
      }
      __syncthreads();   // G[H] ready

      if (h == 0) {
        // cell updates for half H (16 cells)
        #pragma unroll
        for (int rbl = 0; rbl < 2; rbl++) {
          #pragma unroll
          for (int reg = 0; reg < 4; reg++) {
            int lr = rbl * 16 + l4 * 4 + reg;
            float2 go2 = *(const float2*)&Gbuf[H][(lr * 128 + jj) * 2];
            int ci = H * 8 + rbl * 4 + reg;
            float gi = sigm(accH[rbl][0][reg] + bA);
            float gf = sigm(accH[rbl][1][reg] + bB);
            float gg = tanh_f(go2.x);
            float go = sigm(go2.y);
            float c = gf * c_st[ci] + gi * gg;
            c_st[ci] = c;
            float hv = go * tanh_f(c);
            int row = H * 32 + lr;
            if (t < T_HIST - 1) {
              int kb = 16 + (jj >> 3);
              int sb = (kb & 24) | ((kb & 7) ^ (row & 7));
              Anxt[row * 256 + sb * 8 + (jj & 7)] = f2bf(hv);
            } else {
              int kb = jj >> 3;
              int sb = (kb & 8) | ((kb & 7) ^ (row & 7));
              Anxt[row * 256 + sb * 8 + (jj & 7)] = f2bf(hv);
            }
          }
        }
      } else if (t < T_HIST - 1) {
        // stage x(t+1) half H into Anxt
        int row = H * 32 + srl;
        int sb = (skb & 8) | ((skb & 7) ^ (row & 7));
        *(short8*)&Anxt[row * 256 + sb * 8] = cvt8(xp[H][0], xp[H][1]);
      }
    }
    __syncthreads();   // Anxt complete (h-writes + x-stage)
  }

  // ---------------- classifier: out = h_temp @ W_cls + out1; one frag per wave ----------------
  {
    const unsigned short* Afin = &Abuf[0][0];   // t=7 wrote Anxt = Abuf[0] x-region
    int rbo = w >> 2, cbo = w & 3;
    int col = cbo * 16 + l15;
    float ov[4];
    #pragma unroll
    for (int reg = 0; reg < 4; reg++) {
      int row = rbo * 16 + l4 * 4 + reg;
      int node = base + row;
      ov[reg] = (node < N_NODES) ? out1[(size_t)node * OUT_DIM + col] : 0.f;
    }
    f32x4 o = {0.f, 0.f, 0.f, 0.f};
    #pragma unroll
    for (int kk = 0; kk < 4; kk++) {
      short8 bv = *(const short8*)&Wc2[((cbo * 4 + kk) * 64 + lane) * 8];
      int row = rbo * 16 + l15;
      int kb = kk * 4 + l4;
      int sb = (kb & 8) | ((kb & 7) ^ (row & 7));
      short8 a = *(const short8*)&Afin[row * 256 + sb * 8];
      o = __builtin_amdgcn_mfma_f32_16x16x32_bf16(a, bv, o, 0, 0, 0);
    }
    #pragma unroll
    for (int reg = 0; reg < 4; reg++) {
      int row = rbo * 16 + l4 * 4 + reg;
      int node = base + row;
      if (node < N_NODES) out[(size_t)node * OUT_DIM + col] = o[reg] + ov[reg];
    }
  }
}

// ---------------- launch ----------------
extern "C" void kernel_launch(void* const* d_in, const int* in_sizes, int n_in,
                              void* d_out, int out_size, void* d_ws, size_t ws_size,
                              hipStream_t stream) {
  (void)in_sizes; (void)n_in; (void)out_size; (void)ws_size;
  const float* node_feats = (const float*)d_in[0];
  const float* hist       = (const float*)d_in[1];
  const int*   src        = (const int*)d_in[2];
  const int*   dst        = (const int*)d_in[3];
  const float* W_self     = (const float*)d_in[4];
  const float* W_neigh    = (const float*)d_in[5];
  const float* b_sage     = (const float*)d_in[6];
  const float* w_ih       = (const float*)d_in[7];
  const float* w_hh       = (const float*)d_in[8];
  const float* b_lstm     = (const float*)d_in[9];
  const float* W_cls      = (const float*)d_in[10];
  const float* b_cls      = (const float*)d_in[11];
  float* out = (float*)d_out;

  char* ws = (char*)d_ws;
  int* cnt        = (int*)(ws);                        // 200,000 -> 200,192
  int* rowstart   = (int*)(ws + 200192);               // 200,000 -> 400,384
  int* cursor     = (int*)(ws + 400384);               // 200,000 -> 600,576
  int* esrc       = (int*)(ws + 600576);               // 3,200,000 -> 3,800,576
  float* out1     = (float*)(ws + 3800576);            // 12,800,000 -> 16,600,576
  unsigned short* Wt2 = (unsigned short*)(ws + 16600576);  // 262,144 -> 16,862,720
  unsigned short* Wc2 = (unsigned short*)(ws + 16862720);  // 16,384 -> 16,879,104
  float* Wsc      = (float*)(ws + 16879104);           // 16,384 -> 16,895,488
  float* Wnc      = (float*)(ws + 16895488);           // 16,384 -> 16,911,872
  float* bc1      = (float*)(ws + 16911872);           // 256

  prepack_kernel<<<128, 256, 0, stream>>>(w_ih, w_hh, W_cls, W_self, W_neigh, b_sage, b_cls,
                                          Wt2, Wc2, Wsc, Wnc, bc1, cnt);
  count_kernel<<<(N_EDGES + 255) / 256, 256, 0, stream>>>(dst, cnt);
  scan_kernel<<<1, 1024, 0, stream>>>(cnt, rowstart, cursor);
  fill_kernel<<<(N_EDGES + 255) / 256, 256, 0, stream>>>(src, dst, cursor, esrc);
  hstruct_kernel<<<(N_NODES + HS_TILE - 1) / HS_TILE, 256, 0, stream>>>(
      node_feats, esrc, rowstart, cnt, Wsc, Wnc, bc1, out1);
  lstm_kernel<<<(N_NODES + LB - 1) / LB, 1024, 0, stream>>>(
      hist, Wt2, Wc2, b_lstm, out1, out);
}

// Round 8
// 597.633 us; speedup vs baseline: 1.0975x; 1.0975x over previous
//
#include <hip/hip_runtime.h>
#include <hip/hip_bf16.h>
#include <hip/hip_cooperative_groups.h>
#include <stdint.h>

namespace cg = cooperative_groups;

#define N_NODES 50000
#define N_EDGES 800000
#define IN_DIM 64
#define HID 128
#define OUT_DIM 64
#define T_HIST 8

#define GB 256   // cooperative grid blocks
#define GT 512   // threads per block
#define NPB 196  // nodes per block for scan (196*256 = 50176 >= 50000)

typedef __attribute__((ext_vector_type(8))) short short8;
typedef __attribute__((ext_vector_type(4))) float f32x4;

__device__ __forceinline__ unsigned short f2bf(float x) {
  unsigned int u = __builtin_bit_cast(unsigned int, x);
  unsigned int r = (u + 0x7FFFu + ((u >> 16) & 1u)) >> 16;
  return (unsigned short)r;
}
__device__ __forceinline__ short8 cvt8(float4 a, float4 b) {
  unsigned int w0, w1, w2, w3;
  asm("v_cvt_pk_bf16_f32 %0, %1, %2" : "=v"(w0) : "v"(a.x), "v"(a.y));
  asm("v_cvt_pk_bf16_f32 %0, %1, %2" : "=v"(w1) : "v"(a.z), "v"(a.w));
  asm("v_cvt_pk_bf16_f32 %0, %1, %2" : "=v"(w2) : "v"(b.x), "v"(b.y));
  asm("v_cvt_pk_bf16_f32 %0, %1, %2" : "=v"(w3) : "v"(b.z), "v"(b.w));
  struct { unsigned int a, b, c, d; } s{w0, w1, w2, w3};
  return __builtin_bit_cast(short8, s);
}
// sigmoid/tanh via exp2+rcp; safe at +-inf
__device__ __forceinline__ float sigm(float x) {
  float e = __builtin_amdgcn_exp2f(-1.4426950408889634f * x);
  return __builtin_amdgcn_rcpf(1.f + e);
}
__device__ __forceinline__ float tanh_f(float x) {
  float e = __builtin_amdgcn_exp2f(2.8853900817779268f * x);
  return 1.f - 2.f * __builtin_amdgcn_rcpf(e + 1.f);
}

// ================= cooperative graph kernel =================
// P0 prepack+zero -> P1 count -> P2 scan -> P3 fill -> P4 hstruct(out1)
__global__ __launch_bounds__(GT) void graph_kernel(
    const float* __restrict__ nf, const int* __restrict__ src, const int* __restrict__ dst,
    const float* __restrict__ w_ih, const float* __restrict__ w_hh, const float* __restrict__ W_cls,
    const float* __restrict__ W_self, const float* __restrict__ W_neigh,
    const float* __restrict__ b_sage, const float* __restrict__ b_cls,
    unsigned short* __restrict__ Wt2, unsigned short* __restrict__ Wc2,
    float* __restrict__ Wsc, float* __restrict__ Wnc, float* __restrict__ bc1,
    int* __restrict__ cnt, int* __restrict__ lexcl, int* __restrict__ rowstart,
    int* __restrict__ cursor, int* __restrict__ btot, int* __restrict__ bbase,
    int* __restrict__ esrc, float* __restrict__ out1)
{
  cg::grid_group grid = cg::this_grid();
  __shared__ int sh[GT];
  __shared__ float s_nf[32][IN_DIM + 1];
  __shared__ float s_hn[32][IN_DIM + 1];

  const int tid = threadIdx.x;
  const int gid = blockIdx.x;
  const int gtid = gid * GT + tid;
  const int GS = GB * GT;

  // ---- P0: zero cnt + prepack all weight forms ----
  for (int i = gtid; i < N_NODES; i += GS) cnt[i] = 0;
  for (int idx = gtid; idx < 256 * 512; idx += GS) {
    int i = idx & 7;
    int lane = (idx >> 3) & 63;
    int F = idx >> 9;
    int q = F >> 5, g = (F >> 3) & 3, kk = F & 7;
    int c = g * 128 + q * 16 + (lane & 15);
    int k = kk * 32 + (lane >> 4) * 8 + i;
    float v = (k < 128) ? w_ih[k * 512 + c] : w_hh[(k - 128) * 512 + c];
    Wt2[idx] = f2bf(v);
  }
  for (int idx = gtid; idx < 16 * 512; idx += GS) {
    int i = idx & 7;
    int lane = (idx >> 3) & 63;
    int F = idx >> 9;
    int cb = F >> 2, kk = F & 3;
    int col = cb * 16 + (lane & 15);
    int k = kk * 32 + (lane >> 4) * 8 + i;
    Wc2[idx] = f2bf(W_cls[k * 64 + col]);
  }
  for (int idx = gtid; idx < 64 * 64; idx += GS) {
    int k = idx >> 6, c = idx & 63;
    float as = 0.f, an = 0.f;
    for (int m = 0; m < 128; m++) {
      float wc = W_cls[m * 64 + c];
      as += W_self[k * 128 + m] * wc;
      an += W_neigh[k * 128 + m] * wc;
    }
    Wsc[idx] = as;
    Wnc[idx] = an;
  }
  for (int c = gtid; c < 64; c += GS) {
    float acc = b_cls[c];
    for (int m = 0; m < 128; m++) acc += b_sage[m] * W_cls[m * 64 + c];
    bc1[c] = acc;
  }
  grid.sync();

  // ---- P1: count ----
  for (int e = gtid; e < N_EDGES; e += GS) atomicAdd(&cnt[dst[e]], 1);
  grid.sync();

  // ---- P2a: block-local exclusive scan over NPB nodes ----
  {
    int i0 = gid * NPB;
    int i = i0 + tid;
    int v = (tid < NPB && i < N_NODES) ? cnt[i] : 0;
    sh[tid] = v;
    __syncthreads();
    int val = v;
    for (int off = 1; off < GT; off <<= 1) {
      int x = (tid >= off) ? sh[tid - off] : 0;
      __syncthreads();
      val += x;
      sh[tid] = val;
      __syncthreads();
    }
    if (tid < NPB && i < N_NODES) lexcl[i] = val - v;
    if (tid == GT - 1) btot[gid] = val;
  }
  grid.sync();

  // ---- P2b: block 0 scans btot[GB] ----
  if (gid == 0) {
    int v = (tid < GB) ? btot[tid] : 0;
    sh[tid] = v;
    __syncthreads();
    int val = v;
    for (int off = 1; off < GT; off <<= 1) {
      int x = (tid >= off) ? sh[tid - off] : 0;
      __syncthreads();
      val += x;
      sh[tid] = val;
      __syncthreads();
    }
    if (tid < GB) bbase[tid] = val - v;
  }
  grid.sync();

  // ---- P2c: rowstart / cursor ----
  for (int i = gtid; i < N_NODES; i += GS) {
    int rs = lexcl[i] + bbase[i / NPB];
    rowstart[i] = rs;
    cursor[i] = rs;
  }
  grid.sync();

  // ---- P3: fill ----
  for (int e = gtid; e < N_EDGES; e += GS) {
    int d = dst[e];
    int pos = atomicAdd(&cursor[d], 1);
    esrc[pos] = src[e];
  }
  grid.sync();

  // ---- P4: out1 = nf@Wsc + mean_neigh@Wnc + bc1 (32-row tiles) ----
  const int NT = (N_NODES + 31) / 32;
  const int wv = tid >> 6, lane = tid & 63;
  for (int tile = gid; tile < NT; tile += GB) {
    int node0 = tile * 32;
    __syncthreads();   // protect LDS reuse across tile iterations
    for (int i = tid; i < 32 * IN_DIM; i += GT) {
      int r = i >> 6, k = i & 63;
      int node = node0 + r;
      s_nf[r][k] = (node < N_NODES) ? nf[node * 64 + k] : 0.f;
    }
    for (int r = wv; r < 32; r += 8) {   // 8 waves x 4 rows
      int node = node0 + r;
      float a0 = 0.f, a1 = 0.f, a2 = 0.f, a3 = 0.f;
      int n = 0;
      if (node < N_NODES) {
        n = cnt[node];
        int st = rowstart[node];
        int j = 0;
        for (; j + 4 <= n; j += 4) {
          int s0 = esrc[st + j], s1 = esrc[st + j + 1];
          int s2 = esrc[st + j + 2], s3 = esrc[st + j + 3];
          a0 += nf[s0 * 64 + lane];
          a1 += nf[s1 * 64 + lane];
          a2 += nf[s2 * 64 + lane];
          a3 += nf[s3 * 64 + lane];
        }
        for (; j < n; j++) a0 += nf[esrc[st + j] * 64 + lane];
      }
      s_hn[r][lane] = (a0 + a1 + a2 + a3) * __builtin_amdgcn_rcpf(fmaxf((float)n, 1.f));
    }
    __syncthreads();
    // GEMM: 512 threads, r = tid&31, 16 col-groups x 4 cols
    int r = tid & 31;
    int c0 = (tid >> 5) * 4;
    float accs[4] = {0.f, 0.f, 0.f, 0.f};
    for (int k = 0; k < IN_DIM; k++) {
      float a = s_nf[r][k];
      float b = s_hn[r][k];
      float4 w1 = *(const float4*)&Wsc[k * 64 + c0];
      float4 w2 = *(const float4*)&Wnc[k * 64 + c0];
      accs[0] += a * w1.x + b * w2.x;
      accs[1] += a * w1.y + b * w2.y;
      accs[2] += a * w1.z + b * w2.z;
      accs[3] += a * w1.w + b * w2.w;
    }
    int node = node0 + r;
    if (node < N_NODES) {
      #pragma unroll
      for (int i = 0; i < 4; i++)
        out1[(size_t)node * 64 + c0 + i] = accs[i] + bc1[c0 + i];
    }
  }
}

// ---------------- fused LSTM (8 steps) + classifier, W in registers ----------------
// R6-proven structure (byte-identical): 512 thr = 8 waves, 64 nodes/block,
// wave owns 16 cols x 4 gates, 4 row-block passes, double-buffered A, 1 barrier/step.
#define LB 64
__global__ __launch_bounds__(512, 2) void lstm_kernel(
    const float* __restrict__ hist,          // [N][8][128] f32
    const unsigned short* __restrict__ Wt2,  // frag-ordered bf16
    const unsigned short* __restrict__ Wc2,  // frag-ordered bf16
    const float* __restrict__ b_lstm,        // [512]
    const float* __restrict__ out1,          // [N][64] fp32 (classifier partial)
    float* __restrict__ out)                 // [N][64]
{
  __shared__ alignas(16) unsigned short Abuf[2][64 * 256];  // 2 x 32KB, [row][swz(kb)][8]

  const int tid = threadIdx.x;
  const int lane = tid & 63;
  const int w = tid >> 6;
  const int l15 = lane & 15;
  const int l4 = lane >> 4;
  const int base = blockIdx.x * LB;
  const int jj = w * 16 + l15;     // hidden unit owned by this lane

  // persistent B fragments: Bfr[g][kk]  (128 VGPR)
  short8 Bfr[4][8];
  #pragma unroll
  for (int g = 0; g < 4; g++)
    #pragma unroll
    for (int kk = 0; kk < 8; kk++)
      Bfr[g][kk] = *(const short8*)&Wt2[((w * 32 + g * 8 + kk) * 64 + lane) * 8];

  const float bi  = b_lstm[jj];
  const float bf_ = b_lstm[128 + jj];
  const float bg  = b_lstm[256 + jj];
  const float bo  = b_lstm[384 + jj];

  float c_st[16];
  #pragma unroll
  for (int i = 0; i < 16; i++) c_st[i] = 0.f;

  // prologue: zero h-region of buf0, stage x(0) into buf0
  for (int u = tid; u < 64 * 16; u += 512) {
    int row = u >> 4;
    int kbh = u & 15;
    short8 z = {0,0,0,0,0,0,0,0};
    *(short8*)&Abuf[0][row * 256 + 128 + kbh * 8] = z;
  }
  #pragma unroll
  for (int i2 = 0; i2 < 2; i2++) {
    int u = tid + (i2 << 9);
    int row = u >> 4;
    int kb = u & 15;
    int node = base + row;
    float4 x0 = make_float4(0.f,0.f,0.f,0.f), x1 = make_float4(0.f,0.f,0.f,0.f);
    if (node < N_NODES) {
      const float4* p = (const float4*)&hist[(size_t)node * (T_HIST * HID) + kb * 8];
      x0 = p[0]; x1 = p[1];
    }
    int sb = (kb & 8) | ((kb & 7) ^ (row & 7));
    *(short8*)&Abuf[0][row * 256 + sb * 8] = cvt8(x0, x1);
  }
  __syncthreads();

  float4 xp[4];  // prefetch regs (16 VGPR)

  // ---- steps 0..6 ----
  #pragma unroll
  for (int t = 0; t < T_HIST - 1; t++) {
    unsigned short* Acur = &Abuf[t & 1][0];
    unsigned short* Anxt = &Abuf[(t & 1) ^ 1][0];

    // issue x(t+1) global loads early: latency hides under MFMA phase
    #pragma unroll
    for (int i2 = 0; i2 < 2; i2++) {
      int u = tid + (i2 << 9);
      int row = u >> 4;
      int kb = u & 15;
      int node = base + row;
      if (node < N_NODES) {
        const float4* p = (const float4*)&hist[(size_t)node * (T_HIST * HID) + (t + 1) * HID + kb * 8];
        xp[i2 * 2]     = p[0];
        xp[i2 * 2 + 1] = p[1];
      } else {
        xp[i2 * 2]     = make_float4(0.f,0.f,0.f,0.f);
        xp[i2 * 2 + 1] = make_float4(0.f,0.f,0.f,0.f);
      }
    }

    // 4 row-block passes; acc (16 VGPR) dies at end of each pass
    #pragma unroll
    for (int rb = 0; rb < 4; rb++) {
      f32x4 acc[4];
      #pragma unroll
      for (int g = 0; g < 4; g++) { f32x4 z = {0.f,0.f,0.f,0.f}; acc[g] = z; }
      #pragma unroll
      for (int kk = 0; kk < 8; kk++) {
        int row = rb * 16 + l15;
        int kb = kk * 4 + l4;
        int sb = (kb & 24) | ((kb & 7) ^ (row & 7));
        short8 a = *(const short8*)&Acur[row * 256 + sb * 8];
        #pragma unroll
        for (int g = 0; g < 4; g++)
          acc[g] = __builtin_amdgcn_mfma_f32_16x16x32_bf16(a, Bfr[g][kk], acc[g], 0, 0, 0);
      }
      // cell update for this row block; h -> Anxt h-region
      #pragma unroll
      for (int reg = 0; reg < 4; reg++) {
        int r = rb * 4 + reg;
        float gi = sigm(acc[0][reg] + bi);
        float gf = sigm(acc[1][reg] + bf_);
        float gg = tanh_f(acc[2][reg] + bg);
        float go = sigm(acc[3][reg] + bo);
        float c = gf * c_st[r] + gi * gg;
        c_st[r] = c;
        float h = go * tanh_f(c);
        int row = rb * 16 + l4 * 4 + reg;
        int kb = 16 + (jj >> 3);
        int sb = (kb & 24) | ((kb & 7) ^ (row & 7));
        Anxt[row * 256 + sb * 8 + (jj & 7)] = f2bf(h);
      }
      __builtin_amdgcn_sched_barrier(0);  // keep passes separate: acc stays 16 regs
    }

    // write staged x(t+1) into next buffer's x-region
    #pragma unroll
    for (int i2 = 0; i2 < 2; i2++) {
      int u = tid + (i2 << 9);
      int row = u >> 4;
      int kb = u & 15;
      int sb = (kb & 8) | ((kb & 7) ^ (row & 7));
      *(short8*)&Anxt[row * 256 + sb * 8] = cvt8(xp[i2 * 2], xp[i2 * 2 + 1]);
    }
    __syncthreads();   // single barrier per step
  }

  // ---- t = 7 (peeled): final step; write h into x-region of Abuf[0] ----
  {
    unsigned short* Acur = &Abuf[1][0];
    unsigned short* Anxt = &Abuf[0][0];

    #pragma unroll
    for (int rb = 0; rb < 4; rb++) {
      f32x4 acc[4];
      #pragma unroll
      for (int g = 0; g < 4; g++) { f32x4 z = {0.f,0.f,0.f,0.f}; acc[g] = z; }
      #pragma unroll
      for (int kk = 0; kk < 8; kk++) {
        int row = rb * 16 + l15;
        int kb = kk * 4 + l4;
        int sb = (kb & 24) | ((kb & 7) ^ (row & 7));
        short8 a = *(const short8*)&Acur[row * 256 + sb * 8];
        #pragma unroll
        for (int g = 0; g < 4; g++)
          acc[g] = __builtin_amdgcn_mfma_f32_16x16x32_bf16(a, Bfr[g][kk], acc[g], 0, 0, 0);
      }
      #pragma unroll
      for (int reg = 0; reg < 4; reg++) {
        int r = rb * 4 + reg;
        float gi = sigm(acc[0][reg] + bi);
        float gf = sigm(acc[1][reg] + bf_);
        float gg = tanh_f(acc[2][reg] + bg);
        float go = sigm(acc[3][reg] + bo);
        float c = gf * c_st[r] + gi * gg;
        float h = go * tanh_f(c);
        int row = rb * 16 + l4 * 4 + reg;
        int kb = jj >> 3;
        int sb = (kb & 8) | ((kb & 7) ^ (row & 7));
        Anxt[row * 256 + sb * 8 + (jj & 7)] = f2bf(h);
      }
      __builtin_amdgcn_sched_barrier(0);
    }
    __syncthreads();

    // classifier: out = h_temp @ W_cls + out1   (Bfr dead -> bc loads here)
    #pragma unroll
    for (int fi = 0; fi < 2; fi++) {
      int f = w * 2 + fi;
      int rbo = f >> 2, cbo = f & 3;
      int col = cbo * 16 + l15;
      // preload out1 partials (coalesced) + W_cls frags
      float ov[4];
      #pragma unroll
      for (int reg = 0; reg < 4; reg++) {
        int row = rbo * 16 + l4 * 4 + reg;
        int node = base + row;
        ov[reg] = (node < N_NODES) ? out1[(size_t)node * OUT_DIM + col] : 0.f;
      }
      f32x4 o = {0.f, 0.f, 0.f, 0.f};
      #pragma unroll
      for (int kk = 0; kk < 4; kk++) {
        short8 bv = *(const short8*)&Wc2[((cbo * 4 + kk) * 64 + lane) * 8];
        int row = rbo * 16 + l15;
        int kb = kk * 4 + l4;
        int sb = (kb & 8) | ((kb & 7) ^ (row & 7));
        short8 a = *(const short8*)&Anxt[row * 256 + sb * 8];
        o = __builtin_amdgcn_mfma_f32_16x16x32_bf16(a, bv, o, 0, 0, 0);
      }
      #pragma unroll
      for (int reg = 0; reg < 4; reg++) {
        int row = rbo * 16 + l4 * 4 + reg;
        int node = base + row;
        if (node < N_NODES) out[(size_t)node * OUT_DIM + col] = o[reg] + ov[reg];
      }
    }
  }
}

// ---------------- launch ----------------
extern "C" void kernel_launch(void* const* d_in, const int* in_sizes, int n_in,
                              void* d_out, int out_size, void* d_ws, size_t ws_size,
                              hipStream_t stream) {
  (void)in_sizes; (void)n_in; (void)out_size; (void)ws_size;
  const float* node_feats = (const float*)d_in[0];
  const float* hist       = (const float*)d_in[1];
  const int*   src        = (const int*)d_in[2];
  const int*   dst        = (const int*)d_in[3];
  const float* W_self     = (const float*)d_in[4];
  const float* W_neigh    = (const float*)d_in[5];
  const float* b_sage     = (const float*)d_in[6];
  const float* w_ih       = (const float*)d_in[7];
  const float* w_hh       = (const float*)d_in[8];
  const float* b_lstm     = (const float*)d_in[9];
  const float* W_cls      = (const float*)d_in[10];
  const float* b_cls      = (const float*)d_in[11];
  float* out = (float*)d_out;

  char* ws = (char*)d_ws;
  int* cnt        = (int*)(ws);                        // 200,192
  int* lexcl      = (int*)(ws + 200192);               // -> 400,384
  int* rowstart   = (int*)(ws + 400384);               // -> 600,576
  int* cursor     = (int*)(ws + 600576);               // -> 800,768
  int* btot       = (int*)(ws + 800768);               // -> 801,792
  int* bbase      = (int*)(ws + 801792);               // -> 802,816
  int* esrc       = (int*)(ws + 802816);               // -> 4,002,816
  float* out1     = (float*)(ws + 4002816);            // -> 16,802,816
  unsigned short* Wt2 = (unsigned short*)(ws + 16802816);  // -> 17,064,960
  unsigned short* Wc2 = (unsigned short*)(ws + 17064960);  // -> 17,081,344
  float* Wsc      = (float*)(ws + 17081344);           // -> 17,097,728
  float* Wnc      = (float*)(ws + 17097728);           // -> 17,114,112
  float* bc1      = (float*)(ws + 17114112);           // -> 17,114,368

  void* args[] = {
    (void*)&node_feats, (void*)&src, (void*)&dst,
    (void*)&w_ih, (void*)&w_hh, (void*)&W_cls,
    (void*)&W_self, (void*)&W_neigh, (void*)&b_sage, (void*)&b_cls,
    (void*)&Wt2, (void*)&Wc2, (void*)&Wsc, (void*)&Wnc, (void*)&bc1,
    (void*)&cnt, (void*)&lexcl, (void*)&rowstart, (void*)&cursor,
    (void*)&btot, (void*)&bbase, (void*)&esrc, (void*)&out1
  };
  hipLaunchCooperativeKernel((void*)graph_kernel, dim3(GB), dim3(GT), args, 0, stream);

  lstm_kernel<<<(N_NODES + LB - 1) / LB, 512, 0, stream>>>(
      hist, Wt2, Wc2, b_lstm, out1, out);
}

// Round 9
// 363.944 us; speedup vs baseline: 1.8022x; 1.6421x over previous
//
#include <hip/hip_runtime.h>
#include <hip/hip_bf16.h>
#include <stdint.h>

#define N_NODES 50000
#define N_EDGES 800000
#define IN_DIM 64
#define HID 128
#define OUT_DIM 64
#define T_HIST 8

#define NB_SCAN ((N_NODES + 1023) / 1024)   // 49 scan blocks, 1024 nodes each

typedef __attribute__((ext_vector_type(8))) short short8;
typedef __attribute__((ext_vector_type(4))) float f32x4;

__device__ __forceinline__ unsigned short f2bf(float x) {
  unsigned int u = __builtin_bit_cast(unsigned int, x);
  unsigned int r = (u + 0x7FFFu + ((u >> 16) & 1u)) >> 16;
  return (unsigned short)r;
}
__device__ __forceinline__ short8 cvt8(float4 a, float4 b) {
  unsigned int w0, w1, w2, w3;
  asm("v_cvt_pk_bf16_f32 %0, %1, %2" : "=v"(w0) : "v"(a.x), "v"(a.y));
  asm("v_cvt_pk_bf16_f32 %0, %1, %2" : "=v"(w1) : "v"(a.z), "v"(a.w));
  asm("v_cvt_pk_bf16_f32 %0, %1, %2" : "=v"(w2) : "v"(b.x), "v"(b.y));
  asm("v_cvt_pk_bf16_f32 %0, %1, %2" : "=v"(w3) : "v"(b.z), "v"(b.w));
  struct { unsigned int a, b, c, d; } s{w0, w1, w2, w3};
  return __builtin_bit_cast(short8, s);
}
// sigmoid/tanh via exp2+rcp; safe at +-inf
__device__ __forceinline__ float sigm(float x) {
  float e = __builtin_amdgcn_exp2f(-1.4426950408889634f * x);
  return __builtin_amdgcn_rcpf(1.f + e);
}
__device__ __forceinline__ float tanh_f(float x) {
  float e = __builtin_amdgcn_exp2f(2.8853900817779268f * x);
  return 1.f - 2.f * __builtin_amdgcn_rcpf(e + 1.f);
}

// ---------------- prepack + count (independent work, fused; cnt pre-zeroed by memset) ----------------
__global__ void pc_kernel(const float* __restrict__ w_ih, const float* __restrict__ w_hh,
                          const float* __restrict__ W_cls,
                          const float* __restrict__ W_self, const float* __restrict__ W_neigh,
                          const float* __restrict__ b_sage, const float* __restrict__ b_cls,
                          const int* __restrict__ dst,
                          unsigned short* __restrict__ Wt2, unsigned short* __restrict__ Wc2,
                          float* __restrict__ Wsc, float* __restrict__ Wnc,
                          float* __restrict__ bc1, int* __restrict__ cnt) {
  int tid = blockIdx.x * blockDim.x + threadIdx.x;
  int stride = gridDim.x * blockDim.x;
  // count (largest share first)
  for (int e = tid; e < N_EDGES; e += stride) atomicAdd(&cnt[dst[e]], 1);
  // Wt2 fragments
  for (int idx = tid; idx < 256 * 512; idx += stride) {
    int i = idx & 7;
    int lane = (idx >> 3) & 63;
    int F = idx >> 9;
    int q = F >> 5, g = (F >> 3) & 3, kk = F & 7;
    int c = g * 128 + q * 16 + (lane & 15);
    int k = kk * 32 + (lane >> 4) * 8 + i;
    float v = (k < 128) ? w_ih[k * 512 + c] : w_hh[(k - 128) * 512 + c];
    Wt2[idx] = f2bf(v);
  }
  // Wc2 fragments
  for (int idx = tid; idx < 16 * 512; idx += stride) {
    int i = idx & 7;
    int lane = (idx >> 3) & 63;
    int F = idx >> 9;
    int cb = F >> 2, kk = F & 3;
    int col = cb * 16 + (lane & 15);
    int k = kk * 32 + (lane >> 4) * 8 + i;
    Wc2[idx] = f2bf(W_cls[k * 64 + col]);
  }
  // folded classifier weights
  for (int idx = tid; idx < 64 * 64; idx += stride) {
    int k = idx >> 6, c = idx & 63;
    float as = 0.f, an = 0.f;
    for (int m = 0; m < 128; m++) {
      float wc = W_cls[m * 64 + c];
      as += W_self[k * 128 + m] * wc;
      an += W_neigh[k * 128 + m] * wc;
    }
    Wsc[idx] = as;
    Wnc[idx] = an;
  }
  for (int c = tid; c < 64; c += stride) {
    float acc = b_cls[c];
    for (int m = 0; m < 128; m++) acc += b_sage[m] * W_cls[m * 64 + c];
    bc1[c] = acc;
  }
}

// ---------------- scan1: block-local exclusive scan (1024 nodes/block) ----------------
__global__ __launch_bounds__(256) void scan1_kernel(const int* __restrict__ cnt,
                                                    int* __restrict__ lexcl, int* __restrict__ btot) {
  __shared__ int sh[256];
  int tid = threadIdx.x;
  int base = blockIdx.x * 1024 + tid * 4;
  int v[4];
  #pragma unroll
  for (int q = 0; q < 4; q++) {
    int i = base + q;
    v[q] = (i < N_NODES) ? cnt[i] : 0;
  }
  int tsum = v[0] + v[1] + v[2] + v[3];
  sh[tid] = tsum;
  __syncthreads();
  int val = tsum;
  for (int off = 1; off < 256; off <<= 1) {
    int x = (tid >= off) ? sh[tid - off] : 0;
    __syncthreads();
    val += x;
    sh[tid] = val;
    __syncthreads();
  }
  int ex = val - tsum;  // exclusive
  if (tid == 255) btot[blockIdx.x] = val;
  #pragma unroll
  for (int q = 0; q < 4; q++) {
    int i = base + q;
    if (i < N_NODES) lexcl[i] = ex;
    ex += v[q];
  }
}

// ---------------- scan3: rowstart/cursor = lexcl + prefix(btot) (block prefix inline) ----------------
__global__ __launch_bounds__(1024) void scan3_kernel(const int* __restrict__ lexcl,
                                                     const int* __restrict__ btot,
                                                     int* __restrict__ rowstart, int* __restrict__ cursor) {
  int b = blockIdx.x;
  int bs = 0;
  for (int j = 0; j < b; j++) bs += btot[j];   // <=48 L2-hit loads
  int i = b * 1024 + threadIdx.x;
  if (i < N_NODES) {
    int rs = lexcl[i] + bs;
    rowstart[i] = rs;
    cursor[i] = rs;
  }
}

// ---------------- fill ----------------
__global__ void fill_kernel(const int* __restrict__ src, const int* __restrict__ dst,
                            int* __restrict__ cursor, int* __restrict__ esrc) {
  int e = blockIdx.x * blockDim.x + threadIdx.x;
  if (e < N_EDGES) {
    int d = dst[e];
    int pos = atomicAdd(&cursor[d], 1);
    esrc[pos] = src[e];
  }
}

// ---------------- out1 = nf@Wsc + mean_neigh@Wnc + bc1 (folded classifier) ----------------
#define HS_TILE 32
__global__ __launch_bounds__(512) void hstruct_kernel(
    const float* __restrict__ nf, const int* __restrict__ esrc,
    const int* __restrict__ rowstart, const int* __restrict__ cnt,
    const float* __restrict__ Wsc, const float* __restrict__ Wnc, const float* __restrict__ bc1,
    float* __restrict__ out1) {
  __shared__ float s_nf[HS_TILE][IN_DIM + 1];
  __shared__ float s_hn[HS_TILE][IN_DIM + 1];
  int tid = threadIdx.x;
  int node0 = blockIdx.x * HS_TILE;
  for (int i = tid; i < HS_TILE * IN_DIM; i += 512) {
    int r = i >> 6, k = i & 63;
    int node = node0 + r;
    s_nf[r][k] = (node < N_NODES) ? nf[node * 64 + k] : 0.f;
  }
  int wv = tid >> 6, lane = tid & 63;
  for (int r = wv; r < HS_TILE; r += 8) {   // 8 waves x 4 rows: short chains, high TLP
    int node = node0 + r;
    float a0 = 0.f, a1 = 0.f, a2 = 0.f, a3 = 0.f;
    int n = 0;
    if (node < N_NODES) {
      n = cnt[node];
      int st = rowstart[node];
      int j = 0;
      for (; j + 4 <= n; j += 4) {
        int s0 = esrc[st + j], s1 = esrc[st + j + 1];
        int s2 = esrc[st + j + 2], s3 = esrc[st + j + 3];
        a0 += nf[s0 * 64 + lane];
        a1 += nf[s1 * 64 + lane];
        a2 += nf[s2 * 64 + lane];
        a3 += nf[s3 * 64 + lane];
      }
      for (; j < n; j++) a0 += nf[esrc[st + j] * 64 + lane];
    }
    s_hn[r][lane] = (a0 + a1 + a2 + a3) * __builtin_amdgcn_rcpf(fmaxf((float)n, 1.f));
  }
  __syncthreads();
  // GEMM: 512 threads, r = tid&31, 16 col-groups x 4 cols
  int r = tid & 31;
  int c0 = (tid >> 5) * 4;
  float accs[4] = {0.f, 0.f, 0.f, 0.f};
  for (int k = 0; k < IN_DIM; k++) {
    float a = s_nf[r][k];
    float b = s_hn[r][k];
    float4 w1 = *(const float4*)&Wsc[k * 64 + c0];
    float4 w2 = *(const float4*)&Wnc[k * 64 + c0];
    accs[0] += a * w1.x + b * w2.x;
    accs[1] += a * w1.y + b * w2.y;
    accs[2] += a * w1.z + b * w2.z;
    accs[3] += a * w1.w + b * w2.w;
  }
  int node = node0 + r;
  if (node < N_NODES) {
    #pragma unroll
    for (int i = 0; i < 4; i++)
      out1[(size_t)node * 64 + c0 + i] = accs[i] + bc1[c0 + i];
  }
}

// ---------------- fused LSTM (8 steps) + classifier, W in registers ----------------
// R6-proven structure (byte-identical): 512 thr = 8 waves, 64 nodes/block,
// wave owns 16 cols x 4 gates, 4 row-block passes, double-buffered A, 1 barrier/step.
#define LB 64
__global__ __launch_bounds__(512, 2) void lstm_kernel(
    const float* __restrict__ hist,          // [N][8][128] f32
    const unsigned short* __restrict__ Wt2,  // frag-ordered bf16
    const unsigned short* __restrict__ Wc2,  // frag-ordered bf16
    const float* __restrict__ b_lstm,        // [512]
    const float* __restrict__ out1,          // [N][64] fp32 (classifier partial)
    float* __restrict__ out)                 // [N][64]
{
  __shared__ alignas(16) unsigned short Abuf[2][64 * 256];  // 2 x 32KB, [row][swz(kb)][8]

  const int tid = threadIdx.x;
  const int lane = tid & 63;
  const int w = tid >> 6;
  const int l15 = lane & 15;
  const int l4 = lane >> 4;
  const int base = blockIdx.x * LB;
  const int jj = w * 16 + l15;     // hidden unit owned by this lane

  // persistent B fragments: Bfr[g][kk]  (128 VGPR)
  short8 Bfr[4][8];
  #pragma unroll
  for (int g = 0; g < 4; g++)
    #pragma unroll
    for (int kk = 0; kk < 8; kk++)
      Bfr[g][kk] = *(const short8*)&Wt2[((w * 32 + g * 8 + kk) * 64 + lane) * 8];

  const float bi  = b_lstm[jj];
  const float bf_ = b_lstm[128 + jj];
  const float bg  = b_lstm[256 + jj];
  const float bo  = b_lstm[384 + jj];

  float c_st[16];
  #pragma unroll
  for (int i = 0; i < 16; i++) c_st[i] = 0.f;

  // prologue: zero h-region of buf0, stage x(0) into buf0
  for (int u = tid; u < 64 * 16; u += 512) {
    int row = u >> 4;
    int kbh = u & 15;
    short8 z = {0,0,0,0,0,0,0,0};
    *(short8*)&Abuf[0][row * 256 + 128 + kbh * 8] = z;
  }
  #pragma unroll
  for (int i2 = 0; i2 < 2; i2++) {
    int u = tid + (i2 << 9);
    int row = u >> 4;
    int kb = u & 15;
    int node = base + row;
    float4 x0 = make_float4(0.f,0.f,0.f,0.f), x1 = make_float4(0.f,0.f,0.f,0.f);
    if (node < N_NODES) {
      const float4* p = (const float4*)&hist[(size_t)node * (T_HIST * HID) + kb * 8];
      x0 = p[0]; x1 = p[1];
    }
    int sb = (kb & 8) | ((kb & 7) ^ (row & 7));
    *(short8*)&Abuf[0][row * 256 + sb * 8] = cvt8(x0, x1);
  }
  __syncthreads();

  float4 xp[4];  // prefetch regs (16 VGPR)

  // ---- steps 0..6 ----
  #pragma unroll
  for (int t = 0; t < T_HIST - 1; t++) {
    unsigned short* Acur = &Abuf[t & 1][0];
    unsigned short* Anxt = &Abuf[(t & 1) ^ 1][0];

    // issue x(t+1) global loads early: latency hides under MFMA phase
    #pragma unroll
    for (int i2 = 0; i2 < 2; i2++) {
      int u = tid + (i2 << 9);
      int row = u >> 4;
      int kb = u & 15;
      int node = base + row;
      if (node < N_NODES) {
        const float4* p = (const float4*)&hist[(size_t)node * (T_HIST * HID) + (t + 1) * HID + kb * 8];
        xp[i2 * 2]     = p[0];
        xp[i2 * 2 + 1] = p[1];
      } else {
        xp[i2 * 2]     = make_float4(0.f,0.f,0.f,0.f);
        xp[i2 * 2 + 1] = make_float4(0.f,0.f,0.f,0.f);
      }
    }

    // 4 row-block passes; acc (16 VGPR) dies at end of each pass
    #pragma unroll
    for (int rb = 0; rb < 4; rb++) {
      f32x4 acc[4];
      #pragma unroll
      for (int g = 0; g < 4; g++) { f32x4 z = {0.f,0.f,0.f,0.f}; acc[g] = z; }
      #pragma unroll
      for (int kk = 0; kk < 8; kk++) {
        int row = rb * 16 + l15;
        int kb = kk * 4 + l4;
        int sb = (kb & 24) | ((kb & 7) ^ (row & 7));
        short8 a = *(const short8*)&Acur[row * 256 + sb * 8];
        #pragma unroll
        for (int g = 0; g < 4; g++)
          acc[g] = __builtin_amdgcn_mfma_f32_16x16x32_bf16(a, Bfr[g][kk], acc[g], 0, 0, 0);
      }
      // cell update for this row block; h -> Anxt h-region
      #pragma unroll
      for (int reg = 0; reg < 4; reg++) {
        int r = rb * 4 + reg;
        float gi = sigm(acc[0][reg] + bi);
        float gf = sigm(acc[1][reg] + bf_);
        float gg = tanh_f(acc[2][reg] + bg);
        float go = sigm(acc[3][reg] + bo);
        float c = gf * c_st[r] + gi * gg;
        c_st[r] = c;
        float h = go * tanh_f(c);
        int row = rb * 16 + l4 * 4 + reg;
        int kb = 16 + (jj >> 3);
        int sb = (kb & 24) | ((kb & 7) ^ (row & 7));
        Anxt[row * 256 + sb * 8 + (jj & 7)] = f2bf(h);
      }
      __builtin_amdgcn_sched_barrier(0);  // keep passes separate: acc stays 16 regs
    }

    // write staged x(t+1) into next buffer's x-region
    #pragma unroll
    for (int i2 = 0; i2 < 2; i2++) {
      int u = tid + (i2 << 9);
      int row = u >> 4;
      int kb = u & 15;
      int sb = (kb & 8) | ((kb & 7) ^ (row & 7));
      *(short8*)&Anxt[row * 256 + sb * 8] = cvt8(xp[i2 * 2], xp[i2 * 2 + 1]);
    }
    __syncthreads();   // single barrier per step
  }

  // ---- t = 7 (peeled): final step; write h into x-region of Abuf[0] ----
  {
    unsigned short* Acur = &Abuf[1][0];
    unsigned short* Anxt = &Abuf[0][0];

    #pragma unroll
    for (int rb = 0; rb < 4; rb++) {
      f32x4 acc[4];
      #pragma unroll
      for (int g = 0; g < 4; g++) { f32x4 z = {0.f,0.f,0.f,0.f}; acc[g] = z; }
      #pragma unroll
      for (int kk = 0; kk < 8; kk++) {
        int row = rb * 16 + l15;
        int kb = kk * 4 + l4;
        int sb = (kb & 24) | ((kb & 7) ^ (row & 7));
        short8 a = *(const short8*)&Acur[row * 256 + sb * 8];
        #pragma unroll
        for (int g = 0; g < 4; g++)
          acc[g] = __builtin_amdgcn_mfma_f32_16x16x32_bf16(a, Bfr[g][kk], acc[g], 0, 0, 0);
      }
      #pragma unroll
      for (int reg = 0; reg < 4; reg++) {
        int r = rb * 4 + reg;
        float gi = sigm(acc[0][reg] + bi);
        float gf = sigm(acc[1][reg] + bf_);
        float gg = tanh_f(acc[2][reg] + bg);
        float go = sigm(acc[3][reg] + bo);
        float c = gf * c_st[r] + gi * gg;
        float h = go * tanh_f(c);
        int row = rb * 16 + l4 * 4 + reg;
        int kb = jj >> 3;
        int sb = (kb & 8) | ((kb & 7) ^ (row & 7));
        Anxt[row * 256 + sb * 8 + (jj & 7)] = f2bf(h);
      }
      __builtin_amdgcn_sched_barrier(0);
    }
    __syncthreads();

    // classifier: out = h_temp @ W_cls + out1   (Bfr dead -> bc loads here)
    #pragma unroll
    for (int fi = 0; fi < 2; fi++) {
      int f = w * 2 + fi;
      int rbo = f >> 2, cbo = f & 3;
      int col = cbo * 16 + l15;
      // preload out1 partials (coalesced) + W_cls frags
      float ov[4];
      #pragma unroll
      for (int reg = 0; reg < 4; reg++) {
        int row = rbo * 16 + l4 * 4 + reg;
        int node = base + row;
        ov[reg] = (node < N_NODES) ? out1[(size_t)node * OUT_DIM + col] : 0.f;
      }
      f32x4 o = {0.f, 0.f, 0.f, 0.f};
      #pragma unroll
      for (int kk = 0; kk < 4; kk++) {
        short8 bv = *(const short8*)&Wc2[((cbo * 4 + kk) * 64 + lane) * 8];
        int row = rbo * 16 + l15;
        int kb = kk * 4 + l4;
        int sb = (kb & 8) | ((kb & 7) ^ (row & 7));
        short8 a = *(const short8*)&Anxt[row * 256 + sb * 8];
        o = __builtin_amdgcn_mfma_f32_16x16x32_bf16(a, bv, o, 0, 0, 0);
      }
      #pragma unroll
      for (int reg = 0; reg < 4; reg++) {
        int row = rbo * 16 + l4 * 4 + reg;
        int node = base + row;
        if (node < N_NODES) out[(size_t)node * OUT_DIM + col] = o[reg] + ov[reg];
      }
    }
  }
}

// ---------------- launch ----------------
extern "C" void kernel_launch(void* const* d_in, const int* in_sizes, int n_in,
                              void* d_out, int out_size, void* d_ws, size_t ws_size,
                              hipStream_t stream) {
  (void)in_sizes; (void)n_in; (void)out_size; (void)ws_size;
  const float* node_feats = (const float*)d_in[0];
  const float* hist       = (const float*)d_in[1];
  const int*   src        = (const int*)d_in[2];
  const int*   dst        = (const int*)d_in[3];
  const float* W_self     = (const float*)d_in[4];
  const float* W_neigh    = (const float*)d_in[5];
  const float* b_sage     = (const float*)d_in[6];
  const float* w_ih       = (const float*)d_in[7];
  const float* w_hh       = (const float*)d_in[8];
  const float* b_lstm     = (const float*)d_in[9];
  const float* W_cls      = (const float*)d_in[10];
  const float* b_cls      = (const float*)d_in[11];
  float* out = (float*)d_out;

  char* ws = (char*)d_ws;
  int* cnt        = (int*)(ws);                        // 200,192
  int* lexcl      = (int*)(ws + 200192);               // -> 400,384
  int* rowstart   = (int*)(ws + 400384);               // -> 600,576
  int* cursor     = (int*)(ws + 600576);               // -> 800,768
  int* btot       = (int*)(ws + 800768);               // -> 801,792
  int* esrc       = (int*)(ws + 801792);               // -> 4,001,792
  float* out1     = (float*)(ws + 4001792);            // -> 16,801,792
  unsigned short* Wt2 = (unsigned short*)(ws + 16801792);  // -> 17,063,936
  unsigned short* Wc2 = (unsigned short*)(ws + 17063936);  // -> 17,080,320
  float* Wsc      = (float*)(ws + 17080320);           // -> 17,096,704
  float* Wnc      = (float*)(ws + 17096704);           // -> 17,113,088
  float* bc1      = (float*)(ws + 17113088);           // -> 17,113,344

  hipMemsetAsync(cnt, 0, 200000, stream);
  pc_kernel<<<1024, 256, 0, stream>>>(w_ih, w_hh, W_cls, W_self, W_neigh, b_sage, b_cls,
                                      dst, Wt2, Wc2, Wsc, Wnc, bc1, cnt);
  scan1_kernel<<<NB_SCAN, 256, 0, stream>>>(cnt, lexcl, btot);
  scan3_kernel<<<NB_SCAN, 1024, 0, stream>>>(lexcl, btot, rowstart, cursor);
  fill_kernel<<<(N_EDGES + 255) / 256, 256, 0, stream>>>(src, dst, cursor, esrc);
  hstruct_kernel<<<(N_NODES + HS_TILE - 1) / HS_TILE, 512, 0, stream>>>(
      node_feats, esrc, rowstart, cnt, Wsc, Wnc, bc1, out1);
  lstm_kernel<<<(N_NODES + LB - 1) / LB, 512, 0, stream>>>(
      hist, Wt2, Wc2, b_lstm, out1, out);
}